// Round 6
// baseline (184.221 us; speedup 1.0000x reference)
//
#include <hip/hip_runtime.h>
#include <hip/hip_bf16.h>
#include <stdint.h>

// BConv2d: out = conv2d(sign(x), sign(w), pad=1) + b
// N=32, Cin=256, H=W=56, Cout=256, K=3. fp32 in/out.
//
// dot(±1,±1) over 256-bit tap = 256 - 2*popcount(xor). Padded packed-x
// layout [N][58][58][8] with zero borders (zeros == all -1); the false
// border contribution is removed by adj[bt][co] = bias[co] - sum_invalid(...).
//
// R5 lessons: (1) 58KB ostage -> 2 blocks/CU -> latency-bound at 2 waves/SIMD;
// (2) wreg+sliding-window exceeded regalloc budget, compiler re-streamed
// columns. R6: padded xp => 18 imm-offset loads off ONE base ptr (no border
// logic, no 64-bit addr math in loop); int16 ostage (29.7KB -> 4-5 blocks/CU);
// no persistent window (taps are L1-resident).

#define NBATCH 32
#define CIN    256
#define COUT   256
#define HH     56
#define WW     56
#define HW     (HH*WW)          // 3136
#define NPIX   (NBATCH*HW)      // 100352

#define PW    58                // padded width/height
#define PROW  (PW*8)            // 464 words per padded row
#define PIMG  (PW*PW*8)         // 26912 words per padded image

#define XP_BYTES  ((size_t)NBATCH * PIMG * 4)  // 3,444,736
#define WP_BYTES  ((size_t)COUT * 72 * 4)      // 73,728

// ---- zero padded xp (borders must be 0 every call; interior overwritten)
__global__ __launch_bounds__(256) void zero_xp_kernel(uint32_t* __restrict__ xp)
{
    int i = blockIdx.x * 256 + threadIdx.x;    // 841*256 == 215,296 uint4
    *(uint4*)(xp + (size_t)i * 4) = make_uint4(0u, 0u, 0u, 0u);
}

// ---- pack x: wave handles 64 channels (2 words) for 64 pixels (lane=pixel)
__global__ __launch_bounds__(256) void pack_x_kernel(
    const float* __restrict__ x, uint32_t* __restrict__ xp)
{
    int lane = threadIdx.x & 63;
    int wv   = threadIdx.x >> 6;               // 0..3 -> channel group
    int pix  = blockIdx.x * 64 + lane;         // 1568 blocks * 64 == NPIX
    int n  = pix / HW;
    int hw = pix - n * HW;
    int h  = hw / WW;
    int w_ = hw - h * WW;
    const float* xb = x + ((size_t)n * CIN + (size_t)wv * 64) * HW + hw;

    uint32_t w0 = 0, w1 = 0;
    #pragma unroll
    for (int j = 0; j < 32; ++j) {
        w0 |= (xb[(size_t)j * HW]        >= 0.0f ? 1u : 0u) << j;
        w1 |= (xb[(size_t)(j + 32) * HW] >= 0.0f ? 1u : 0u) << j;
    }
    uint32_t* dst = xp + (size_t)n * PIMG + (size_t)(h + 1) * PROW
                       + (size_t)(w_ + 1) * 8 + wv * 2;
    *(uint2*)dst = make_uint2(w0, w1);
}

// ---- pack w (TRANSPOSED): wp_t[k*COUT + co], k = t*8 + wd
__global__ __launch_bounds__(256) void pack_w_kernel(
    const float* __restrict__ w, const float* __restrict__ bias,
    uint32_t* __restrict__ wp_t, float* __restrict__ adj)
{
    int co   = blockIdx.x;
    int ci   = threadIdx.x;                    // 0..255
    int lane = ci & 63, wv = ci >> 6;
    const float* wb = w + ((size_t)co * CIN + ci) * 9;

    float v[9];
    #pragma unroll
    for (int t = 0; t < 9; ++t) v[t] = wb[t];

    __shared__ int pops[4][9];
    __shared__ int popv[9];

    #pragma unroll
    for (int t = 0; t < 9; ++t) {
        unsigned long long m = __ballot(v[t] >= 0.0f);
        if (lane == 0) {
            wp_t[(size_t)(t * 8 + 2 * wv)     * COUT + co] = (uint32_t)m;
            wp_t[(size_t)(t * 8 + 2 * wv + 1) * COUT + co] = (uint32_t)(m >> 32);
            pops[wv][t] = (int)__popcll(m);
        }
    }
    __syncthreads();
    if (ci < 9) popv[ci] = pops[0][ci] + pops[1][ci] + pops[2][ci] + pops[3][ci];
    __syncthreads();
    if (ci < 9) {
        int bt = ci, ht = bt / 3, wt = bt % 3;
        float c = 0.0f;
        #pragma unroll
        for (int t = 0; t < 9; ++t) {
            int dh = t / 3, dw = t % 3;
            bool inv = (ht == 0 && dh == 0) || (ht == 2 && dh == 2) ||
                       (wt == 0 && dw == 0) || (wt == 2 && dw == 2);
            if (inv) c += (float)(CIN - 2 * popv[t]);
        }
        adj[bt * COUT + co] = bias[co] - c;
    }
}

// ---- conv: block=(n,h); lane=co; 18 imm-offset loads per pixel off one base
#define CELL(ACC, r, c) { \
    uint4 u0 = *(const uint4*)(bp + (r) * PROW + (c) * 8); \
    uint4 u1 = *(const uint4*)(bp + (r) * PROW + (c) * 8 + 4); \
    const int kb = ((r) * 3 + (c)) * 8; \
    ACC += __popc(u0.x ^ wreg[kb + 0]); \
    ACC += __popc(u0.y ^ wreg[kb + 1]); \
    ACC += __popc(u0.z ^ wreg[kb + 2]); \
    ACC += __popc(u0.w ^ wreg[kb + 3]); \
    ACC += __popc(u1.x ^ wreg[kb + 4]); \
    ACC += __popc(u1.y ^ wreg[kb + 5]); \
    ACC += __popc(u1.z ^ wreg[kb + 6]); \
    ACC += __popc(u1.w ^ wreg[kb + 7]); }

__global__ __launch_bounds__(256, 3) void bconv_kernel(
    const uint32_t* __restrict__ xp, const uint32_t* __restrict__ wp_t,
    const float* __restrict__ adj, float* __restrict__ out)
{
    __shared__ __align__(8) int16_t ostage[COUT][PW];   // 29,696 B

    int bx = blockIdx.x;                 // 0..1791
    int n  = bx / HH;
    int h  = bx - n * HH;
    int tid  = threadIdx.x;
    int lane = tid & 63;
    int wg   = tid >> 6;
    int co   = wg * 64 + lane;

    // pin this lane's co weights in VGPRs (coalesced, L2-resident)
    uint32_t wreg[72];
    #pragma unroll
    for (int k = 0; k < 72; ++k) wreg[k] = wp_t[(size_t)k * COUT + co];

    int ht = (h == 0) ? 0 : ((h == HH - 1) ? 2 : 1);

    // base: pixel w uses padded rows h..h+2, padded cols w..w+2
    const uint32_t* bp = xp + (size_t)n * PIMG + (size_t)h * PROW;

    #pragma unroll 2
    for (int w_ = 0; w_ < WW; ++w_) {
        int pA = 0, pB = 0, pC = 0, pD = 0;
        CELL(pA, 0, 0) CELL(pB, 0, 1) CELL(pC, 0, 2)
        CELL(pD, 1, 0) CELL(pA, 1, 1) CELL(pB, 1, 2)
        CELL(pC, 2, 0) CELL(pD, 2, 1) CELL(pA, 2, 2)
        int pop = (pA + pB) + (pC + pD);
        ostage[co][w_] = (int16_t)(2304 - 2 * pop);
        bp += 8;
    }

    __syncthreads();

    // coalesced flush: 3584 float4 per block, 14 per thread; adj added here
    float* ob = out + (size_t)n * COUT * HW + (size_t)h * WW;
    #pragma unroll
    for (int k = 0; k < 14; ++k) {
        int e4  = k * 256 + tid;                   // 0..3583
        int co2 = e4 / 14;
        int q   = e4 - co2 * 14;
        int c0  = 4 * q;
        float a_m = adj[(ht * 3 + 1) * COUT + co2];
        float a_0 = (q == 0)  ? adj[(ht * 3 + 0) * COUT + co2] : a_m;
        float a_3 = (q == 13) ? adj[(ht * 3 + 2) * COUT + co2] : a_m;
        float4 v;
        v.x = (float)ostage[co2][c0 + 0] + a_0;
        v.y = (float)ostage[co2][c0 + 1] + a_m;
        v.z = (float)ostage[co2][c0 + 2] + a_m;
        v.w = (float)ostage[co2][c0 + 3] + a_3;
        *(float4*)(ob + (size_t)co2 * HW + c0) = v;
    }
}

extern "C" void kernel_launch(void* const* d_in, const int* in_sizes, int n_in,
                              void* d_out, int out_size, void* d_ws, size_t ws_size,
                              hipStream_t stream) {
    const float* x = (const float*)d_in[0];
    const float* w = (const float*)d_in[1];
    const float* b = (const float*)d_in[2];
    float* out = (float*)d_out;

    uint32_t* xp   = (uint32_t*)d_ws;
    uint32_t* wpck = (uint32_t*)((char*)d_ws + XP_BYTES);
    float*    adjp = (float*)((char*)d_ws + XP_BYTES + WP_BYTES);

    zero_xp_kernel<<<841, 256, 0, stream>>>(xp);           // 841*256*16B == XP
    pack_x_kernel<<<NPIX / 64, 256, 0, stream>>>(x, xp);
    pack_w_kernel<<<COUT, 256, 0, stream>>>(w, b, wpck, adjp);

    bconv_kernel<<<NBATCH * HH, 256, 0, stream>>>(xp, wpck, adjp, out);
}

// Round 7
// 156.204 us; speedup vs baseline: 1.1794x; 1.1794x over previous
//
#include <hip/hip_runtime.h>
#include <hip/hip_bf16.h>
#include <stdint.h>

// BConv2d: out = conv2d(sign(x), sign(w), pad=1) + b
// N=32, Cin=256, H=W=56, Cout=256, K=3. fp32 in/out.
//
// dot(±1,±1) over 256-bit tap = 256 - 2*popcount(xor). Padded packed-x
// layout [N][58][58][8] with zero borders (zeros == all -1); false border
// contribution removed by adj[bt][co] = bias[co] - sum_invalid(...).
//
// R6 lesson: compiler rematerialized wreg[72] inside the loop (VGPR=76!)
// -> 18 extra per-lane dwordx4 loads/pixel (L1-bound) + addr VALU.
// R7: (1) wreg pinned via asm volatile("":"+v") -- a pinned value cannot be
// rematerialized through an asm barrier; (2) popcount-accumulate emitted as
// fused v_bcnt_u32_b32 acc,src,acc inline asm -> guaranteed 2 VALU/word;
// (3) no LDS staging, direct per-lane stores (write set ~57KB/block in L2);
// (4) launch_bounds(256,4) -> VGPR<=128 -> 4 waves/SIMD.

#define NBATCH 32
#define CIN    256
#define COUT   256
#define HH     56
#define WW     56
#define HW     (HH*WW)          // 3136
#define NPIX   (NBATCH*HW)      // 100352

#define PW    58                // padded width/height
#define PROW  (PW*8)            // 464 words per padded row
#define PIMG  (PW*PW*8)         // 26912 words per padded image

#define XP_BYTES  ((size_t)NBATCH * PIMG * 4)  // 3,444,736
#define WP_BYTES  ((size_t)COUT * 72 * 4)      // 73,728

// ---- zero padded xp (borders must be 0 every call; interior overwritten)
__global__ __launch_bounds__(256) void zero_xp_kernel(uint32_t* __restrict__ xp)
{
    int i = blockIdx.x * 256 + threadIdx.x;    // 841*256 == 215,296 uint4
    *(uint4*)(xp + (size_t)i * 4) = make_uint4(0u, 0u, 0u, 0u);
}

// ---- pack x: wave handles 64 channels (2 words) for 64 pixels (lane=pixel)
__global__ __launch_bounds__(256) void pack_x_kernel(
    const float* __restrict__ x, uint32_t* __restrict__ xp)
{
    int lane = threadIdx.x & 63;
    int wv   = threadIdx.x >> 6;               // 0..3 -> channel group
    int pix  = blockIdx.x * 64 + lane;         // 1568 blocks * 64 == NPIX
    int n  = pix / HW;
    int hw = pix - n * HW;
    int h  = hw / WW;
    int w_ = hw - h * WW;
    const float* xb = x + ((size_t)n * CIN + (size_t)wv * 64) * HW + hw;

    uint32_t w0 = 0, w1 = 0;
    #pragma unroll
    for (int j = 0; j < 32; ++j) {
        w0 |= (xb[(size_t)j * HW]        >= 0.0f ? 1u : 0u) << j;
        w1 |= (xb[(size_t)(j + 32) * HW] >= 0.0f ? 1u : 0u) << j;
    }
    uint32_t* dst = xp + (size_t)n * PIMG + (size_t)(h + 1) * PROW
                       + (size_t)(w_ + 1) * 8 + wv * 2;
    *(uint2*)dst = make_uint2(w0, w1);
}

// ---- pack w (TRANSPOSED): wp_t[k*COUT + co], k = t*8 + wd
__global__ __launch_bounds__(256) void pack_w_kernel(
    const float* __restrict__ w, const float* __restrict__ bias,
    uint32_t* __restrict__ wp_t, float* __restrict__ adj)
{
    int co   = blockIdx.x;
    int ci   = threadIdx.x;                    // 0..255
    int lane = ci & 63, wv = ci >> 6;
    const float* wb = w + ((size_t)co * CIN + ci) * 9;

    float v[9];
    #pragma unroll
    for (int t = 0; t < 9; ++t) v[t] = wb[t];

    __shared__ int pops[4][9];
    __shared__ int popv[9];

    #pragma unroll
    for (int t = 0; t < 9; ++t) {
        unsigned long long m = __ballot(v[t] >= 0.0f);
        if (lane == 0) {
            wp_t[(size_t)(t * 8 + 2 * wv)     * COUT + co] = (uint32_t)m;
            wp_t[(size_t)(t * 8 + 2 * wv + 1) * COUT + co] = (uint32_t)(m >> 32);
            pops[wv][t] = (int)__popcll(m);
        }
    }
    __syncthreads();
    if (ci < 9) popv[ci] = pops[0][ci] + pops[1][ci] + pops[2][ci] + pops[3][ci];
    __syncthreads();
    if (ci < 9) {
        int bt = ci, ht = bt / 3, wt = bt % 3;
        float c = 0.0f;
        #pragma unroll
        for (int t = 0; t < 9; ++t) {
            int dh = t / 3, dw = t % 3;
            bool inv = (ht == 0 && dh == 0) || (ht == 2 && dh == 2) ||
                       (wt == 0 && dw == 0) || (wt == 2 && dw == 2);
            if (inv) c += (float)(CIN - 2 * popv[t]);
        }
        adj[bt * COUT + co] = bias[co] - c;
    }
}

// ---- conv: block=(n,h); lane=co; x via scalar loads (uniform), weights
// pinned in VGPRs, fused v_bcnt accumulate via inline asm.
#define CELL(r, c) { \
    uint4 u0 = *(const uint4*)(bp + (r) * PROW + (c) * 8); \
    uint4 u1 = *(const uint4*)(bp + (r) * PROW + (c) * 8 + 4); \
    const int kb = ((r) * 3 + (c)) * 8; \
    uint32_t t0 = u0.x ^ wreg[kb + 0]; \
    asm("v_bcnt_u32_b32 %0, %1, %0" : "+v"(a0) : "v"(t0)); \
    uint32_t t1 = u0.y ^ wreg[kb + 1]; \
    asm("v_bcnt_u32_b32 %0, %1, %0" : "+v"(a1) : "v"(t1)); \
    uint32_t t2 = u0.z ^ wreg[kb + 2]; \
    asm("v_bcnt_u32_b32 %0, %1, %0" : "+v"(a2) : "v"(t2)); \
    uint32_t t3 = u0.w ^ wreg[kb + 3]; \
    asm("v_bcnt_u32_b32 %0, %1, %0" : "+v"(a3) : "v"(t3)); \
    uint32_t t4 = u1.x ^ wreg[kb + 4]; \
    asm("v_bcnt_u32_b32 %0, %1, %0" : "+v"(a0) : "v"(t4)); \
    uint32_t t5 = u1.y ^ wreg[kb + 5]; \
    asm("v_bcnt_u32_b32 %0, %1, %0" : "+v"(a1) : "v"(t5)); \
    uint32_t t6 = u1.z ^ wreg[kb + 6]; \
    asm("v_bcnt_u32_b32 %0, %1, %0" : "+v"(a2) : "v"(t6)); \
    uint32_t t7 = u1.w ^ wreg[kb + 7]; \
    asm("v_bcnt_u32_b32 %0, %1, %0" : "+v"(a3) : "v"(t7)); }

__global__ __launch_bounds__(256, 4) void bconv_kernel(
    const uint32_t* __restrict__ xp, const uint32_t* __restrict__ wp_t,
    const float* __restrict__ adj, float* __restrict__ out)
{
    int bx = blockIdx.x;                 // 0..1791
    int n  = bx / HH;
    int h  = bx - n * HH;
    int tid  = threadIdx.x;
    int lane = tid & 63;
    int wg   = tid >> 6;
    int co   = wg * 64 + lane;

    // pin this lane's co weights in VGPRs (coalesced, L2-resident)
    uint32_t wreg[72];
    #pragma unroll
    for (int k = 0; k < 72; ++k) wreg[k] = wp_t[(size_t)k * COUT + co];
    #pragma unroll
    for (int k = 0; k < 72; ++k) asm volatile("" : "+v"(wreg[k]));

    int ht = (h == 0) ? 0 : ((h == HH - 1) ? 2 : 1);
    float f_l = 2304.0f + adj[(ht * 3 + 0) * COUT + co];
    float f_m = 2304.0f + adj[(ht * 3 + 1) * COUT + co];
    float f_r = 2304.0f + adj[(ht * 3 + 2) * COUT + co];

    // base: pixel w uses padded rows h..h+2, padded cols w..w+2 (uniform addr)
    const uint32_t* bp = xp + (size_t)n * PIMG + (size_t)h * PROW;
    float* outp = out + ((size_t)n * COUT + co) * HW + (size_t)h * WW;

    #pragma unroll 2
    for (int w_ = 0; w_ < WW; ++w_) {
        uint32_t a0 = 0, a1 = 0, a2 = 0, a3 = 0;
        CELL(0, 0) CELL(0, 1) CELL(0, 2)
        CELL(1, 0) CELL(1, 1) CELL(1, 2)
        CELL(2, 0) CELL(2, 1) CELL(2, 2)
        uint32_t pop = (a0 + a1) + (a2 + a3);
        float base = (w_ == 0) ? f_l : ((w_ == WW - 1) ? f_r : f_m);
        outp[w_] = fmaf(-2.0f, (float)pop, base);
        bp += 8;
    }
}

extern "C" void kernel_launch(void* const* d_in, const int* in_sizes, int n_in,
                              void* d_out, int out_size, void* d_ws, size_t ws_size,
                              hipStream_t stream) {
    const float* x = (const float*)d_in[0];
    const float* w = (const float*)d_in[1];
    const float* b = (const float*)d_in[2];
    float* out = (float*)d_out;

    uint32_t* xp   = (uint32_t*)d_ws;
    uint32_t* wpck = (uint32_t*)((char*)d_ws + XP_BYTES);
    float*    adjp = (float*)((char*)d_ws + XP_BYTES + WP_BYTES);

    zero_xp_kernel<<<841, 256, 0, stream>>>(xp);           // 841*256*16B == XP
    pack_x_kernel<<<NPIX / 64, 256, 0, stream>>>(x, xp);
    pack_w_kernel<<<COUT, 256, 0, stream>>>(w, b, wpck, adjp);

    bconv_kernel<<<NBATCH * HH, 256, 0, stream>>>(xp, wpck, adjp, out);
}

// Round 8
// 108.597 us; speedup vs baseline: 1.6964x; 1.4384x over previous
//
#include <hip/hip_runtime.h>
#include <stdint.h>

// BConv2d via MFMA i8 implicit GEMM.
// out = conv2d(sign(x), sign(w), pad=1) + b ; N=32, Cin=256, H=W=56, Cout=256, K=3.
//
// sign values as i8 {+1,-1}, zero padding as i8 0 (exact; no border correction
// needed). conv = 9 tap-shifted GEMMs, K=256 each, i32 accumulate via
// v_mfma_i32_32x32x32_i8. A = weights [co][ci], B = x [ci][pixel] (so C col =
// pixel -> coalesced stores). A/B k-slot mapping is the same per-lane
// bijection (16 consecutive ci per lane-half), so correctness is independent
// of the hardware's internal k ordering. C/D layout (verified, guide §3):
// col = lane&31, row = (reg&3) + 8*(reg>>2) + 4*(lane>>5).
//
// Block = (n, 2 output rows): 896 blocks x 512 threads (8 waves).
// - expand bit-packed x -> LDS i8 tile xt[4][66][256] (67.6 KB), XOR-swizzled
//   (byte ^ (col&7)<<4) so ds_read_b128 across 32 pixels is ~4-way not 32-way.
// - wave w = co-tile w (32 co) x 4 pixel-tiles; 4 MFMA / k-step; 288 k-steps;
//   NO barriers in the K-loop (X resident in LDS).
// - A streamed from wq[t][c8][co][32] (576 KB, L2-hot).

#define NBATCH 32
#define CIN    256
#define COUT   256
#define HH     56
#define WW     56
#define HW     (HH*WW)          // 3136
#define NPIX   (NBATCH*HW)      // 100352

#define PW    58                // padded bit-image width/height
#define PROW  (PW*8)            // 464 words per padded row
#define PIMG  (PW*PW*8)         // 26912 words per padded image

#define XP_BYTES  ((size_t)NBATCH * PIMG * 4)  // 3,444,736 (16-aligned)
#define WQ_BYTES  ((size_t)9 * 8 * 256 * 32)   // 589,824

typedef int i32x4  __attribute__((ext_vector_type(4)));
typedef int i32x16 __attribute__((ext_vector_type(16)));

// ---- pack x bits: wave handles 64 channels (2 words) for 64 pixels
__global__ __launch_bounds__(256) void pack_x_kernel(
    const float* __restrict__ x, uint32_t* __restrict__ xp)
{
    int lane = threadIdx.x & 63;
    int wv   = threadIdx.x >> 6;               // 0..3 -> channel group
    int pix  = blockIdx.x * 64 + lane;         // 1568 blocks * 64 == NPIX
    int n  = pix / HW;
    int hw = pix - n * HW;
    int h  = hw / WW;
    int w_ = hw - h * WW;
    const float* xb = x + ((size_t)n * CIN + (size_t)wv * 64) * HW + hw;

    uint32_t w0 = 0, w1 = 0;
    #pragma unroll
    for (int j = 0; j < 32; ++j) {
        w0 |= (xb[(size_t)j * HW]        >= 0.0f ? 1u : 0u) << j;
        w1 |= (xb[(size_t)(j + 32) * HW] >= 0.0f ? 1u : 0u) << j;
    }
    uint32_t* dst = xp + (size_t)n * PIMG + (size_t)(h + 1) * PROW
                       + (size_t)(w_ + 1) * 8 + wv * 2;
    *(uint2*)dst = make_uint2(w0, w1);
}

// ---- pack w -> i8 {+1,-1}, layout wq[t][c8][co][slot], slot = ci&31
__global__ __launch_bounds__(256) void pack_w2_kernel(
    const float* __restrict__ w, int8_t* __restrict__ wq)
{
    int co = blockIdx.x, ci = threadIdx.x;
    const float* wb = w + ((size_t)co * CIN + ci) * 9;
    int c8 = ci >> 5, s = ci & 31;
    #pragma unroll
    for (int t = 0; t < 9; ++t) {
        wq[((size_t)(t * 8 + c8) * 256 + co) * 32 + s] =
            (wb[t] >= 0.0f) ? (int8_t)1 : (int8_t)-1;
    }
}

// ---- conv
__global__ __launch_bounds__(512, 4) void bconv_kernel(
    const uint32_t* __restrict__ xp, const int8_t* __restrict__ wq,
    const float* __restrict__ bias, float* __restrict__ out)
{
    __shared__ __align__(16) int8_t xt[4][66][256];   // 67,584 B
    __shared__ float bsh[256];

    int bx = blockIdx.x;               // 0..895
    int n  = bx / 28;
    int hb = bx - n * 28;
    int h  = hb * 2;                   // output rows h, h+1
    int tid = threadIdx.x, lane = tid & 63, wv = tid >> 6;

    if (tid < 256) bsh[tid] = bias[tid];

    // expand packed sign bits -> i8 (+1/-1); borders & cols>=58 -> 0
    const uint32_t* xpb = xp + (size_t)n * PIMG;
    for (int e = tid; e < 4 * 66 * 64; e += 512) {   // 33 iters exactly
        int pr  = e / (66 * 64);
        int rem = e - pr * (66 * 64);
        int col = rem >> 6;
        int d   = rem & 63;            // output dword = 4 ci
        int prg = h + pr;              // padded global row
        bool val = (prg >= 1) & (prg <= 56) & (col >= 1) & (col <= 56);
        uint32_t wvv = 0;
        if (val) wvv = xpb[(size_t)prg * PROW + col * 8 + (d >> 3)];
        uint32_t nib = (wvv >> ((d & 7) * 4)) & 0xFu;
        uint32_t sp  = (nib * 0x00204081u) & 0x01010101u;   // bit k -> byte k
        uint32_t o   = val ? __builtin_amdgcn_perm(0u, 0x000001FFu, sp) : 0u;
        uint32_t ba  = (uint32_t)((((pr * 66 + col) << 8) | (d << 2))
                                  ^ ((col & 7) << 4));
        *(uint32_t*)((char*)&xt[0][0][0] + ba) = o;
    }
    __syncthreads();

    i32x16 acc0 = {0}, acc1 = {0}, acc2 = {0}, acc3 = {0};

    int l31  = lane & 31;
    int hi16 = (lane >> 5) << 4;
    const int8_t* wql = wq + ((size_t)(wv * 32 + l31)) * 32 + hi16;
    const char* xtb = (const char*)&xt[0][0][0];

    for (int t = 0; t < 9; ++t) {
        int dh = (t * 11) >> 5;        // t/3
        int dw = t - dh * 3;
        int c_ = l31 + dw;             // xt col for pix-tile base 0
        int sw = (c_ & 7) << 4;        // same for col c_+32 (bit5 unaffected)
        int ba0 = (dh * 66 + c_) << 8;         // pt0: row dh,   cols c_
        int ba1 = ba0 + (32 << 8);             // pt1: row dh,   cols c_+32
        int ba2 = ba0 + (66 << 8);             // pt2: row dh+1, cols c_
        int ba3 = ba2 + (32 << 8);             // pt3
        const int8_t* wqt = wql + (size_t)t * 8 * 8192;
        #pragma unroll 4
        for (int c8 = 0; c8 < 8; ++c8) {
            i32x4 a = *(const i32x4*)(wqt + (size_t)c8 * 8192);
            int sx = ((c8 << 5) + hi16) ^ sw;
            i32x4 b0 = *(const i32x4*)(xtb + (sx + ba0));
            i32x4 b1 = *(const i32x4*)(xtb + (sx + ba1));
            i32x4 b2 = *(const i32x4*)(xtb + (sx + ba2));
            i32x4 b3 = *(const i32x4*)(xtb + (sx + ba3));
            acc0 = __builtin_amdgcn_mfma_i32_32x32x32_i8(a, b0, acc0, 0, 0, 0);
            acc1 = __builtin_amdgcn_mfma_i32_32x32x32_i8(a, b1, acc1, 0, 0, 0);
            acc2 = __builtin_amdgcn_mfma_i32_32x32x32_i8(a, b2, acc2, 0, 0, 0);
            acc3 = __builtin_amdgcn_mfma_i32_32x32x32_i8(a, b3, acc3, 0, 0, 0);
        }
    }

    // epilogue: C col = pixel (lane&31), row = (r&3)+8*(r>>2)+4*(lane>>5)
    #define EPI(ACC, PT) { \
        int pix = ((PT) & 1) * 32 + l31; \
        if (pix < WW) { \
            int hg = h + ((PT) >> 1); \
            float* op = out + (size_t)n * COUT * HW + (size_t)hg * WW + pix; \
            _Pragma("unroll") \
            for (int r = 0; r < 16; ++r) { \
                int row = (r & 3) + 8 * (r >> 2) + ((lane >> 5) << 2); \
                int co  = (wv << 5) + row; \
                op[(size_t)co * HW] = (float)ACC[r] + bsh[co]; \
            } \
        } }
    EPI(acc0, 0) EPI(acc1, 1) EPI(acc2, 2) EPI(acc3, 3)
    #undef EPI
}

extern "C" void kernel_launch(void* const* d_in, const int* in_sizes, int n_in,
                              void* d_out, int out_size, void* d_ws, size_t ws_size,
                              hipStream_t stream) {
    const float* x = (const float*)d_in[0];
    const float* w = (const float*)d_in[1];
    const float* b = (const float*)d_in[2];
    float* out = (float*)d_out;

    uint32_t* xp = (uint32_t*)d_ws;
    int8_t*   wq = (int8_t*)((char*)d_ws + XP_BYTES);

    pack_x_kernel<<<NPIX / 64, 256, 0, stream>>>(x, xp);
    pack_w2_kernel<<<COUT, 256, 0, stream>>>(w, wq);

    bconv_kernel<<<NBATCH * (HH / 2), 512, 0, stream>>>(xp, wq, b, out);
}

// Round 9
// 105.674 us; speedup vs baseline: 1.7433x; 1.0277x over previous
//
#include <hip/hip_runtime.h>
#include <stdint.h>

// BConv2d via MFMA i8 implicit GEMM.
// out = conv2d(sign(x), sign(w), pad=1) + b ; N=32, Cin=256, H=W=56, Cout=256, K=3.
//
// sign as i8 {+1,-1}, zero padding as i8 0 (exact, no border correction).
// conv = 9 tap-shifted GEMMs, K=256, i32 acc via v_mfma_i32_32x32x32_i8.
// C/D layout: col=lane&31, row=(reg&3)+8*(reg>>2)+4*(lane>>5) (verified R8).
//
// R8 lesson: K-loop was LDS-pipe-bound (1 ds_read_b128 per MFMA, +4 cyc/read
// bank conflicts -> MfmaUtil 28.5%). R9: (1) loop order dw->c8->dh with B
// fragments b[4 rows][2 colblks] hoisted per (dw,c8): 8 reads / 12 MFMAs
// (ratio 1.5x); (2) 16-slot XOR swizzle (col&15)<<4 -> residual 2-way
// conflicts (free) instead of 4-way.

#define NBATCH 32
#define CIN    256
#define COUT   256
#define HH     56
#define WW     56
#define HW     (HH*WW)          // 3136
#define NPIX   (NBATCH*HW)      // 100352

#define PW    58                // padded bit-image width/height
#define PROW  (PW*8)            // 464 words per padded row
#define PIMG  (PW*PW*8)         // 26912 words per padded image

#define XP_BYTES  ((size_t)NBATCH * PIMG * 4)  // 3,444,736 (16-aligned)
#define WQ_BYTES  ((size_t)9 * 8 * 256 * 32)   // 589,824

typedef int i32x4  __attribute__((ext_vector_type(4)));
typedef int i32x16 __attribute__((ext_vector_type(16)));

// ---- pack x bits: wave handles 64 channels (2 words) for 64 pixels
__global__ __launch_bounds__(256) void pack_x_kernel(
    const float* __restrict__ x, uint32_t* __restrict__ xp)
{
    int lane = threadIdx.x & 63;
    int wv   = threadIdx.x >> 6;               // 0..3 -> channel group
    int pix  = blockIdx.x * 64 + lane;         // 1568 blocks * 64 == NPIX
    int n  = pix / HW;
    int hw = pix - n * HW;
    int h  = hw / WW;
    int w_ = hw - h * WW;
    const float* xb = x + ((size_t)n * CIN + (size_t)wv * 64) * HW + hw;

    uint32_t w0 = 0, w1 = 0;
    #pragma unroll
    for (int j = 0; j < 32; ++j) {
        w0 |= (xb[(size_t)j * HW]        >= 0.0f ? 1u : 0u) << j;
        w1 |= (xb[(size_t)(j + 32) * HW] >= 0.0f ? 1u : 0u) << j;
    }
    uint32_t* dst = xp + (size_t)n * PIMG + (size_t)(h + 1) * PROW
                       + (size_t)(w_ + 1) * 8 + wv * 2;
    *(uint2*)dst = make_uint2(w0, w1);
}

// ---- pack w -> i8 {+1,-1}, layout wq[t][c8][co][slot], slot = ci&31
__global__ __launch_bounds__(256) void pack_w2_kernel(
    const float* __restrict__ w, int8_t* __restrict__ wq)
{
    int co = blockIdx.x, ci = threadIdx.x;
    const float* wb = w + ((size_t)co * CIN + ci) * 9;
    int c8 = ci >> 5, s = ci & 31;
    #pragma unroll
    for (int t = 0; t < 9; ++t) {
        wq[((size_t)(t * 8 + c8) * 256 + co) * 32 + s] =
            (wb[t] >= 0.0f) ? (int8_t)1 : (int8_t)-1;
    }
}

// ---- conv
__global__ __launch_bounds__(512, 4) void bconv_kernel(
    const uint32_t* __restrict__ xp, const int8_t* __restrict__ wq,
    const float* __restrict__ bias, float* __restrict__ out)
{
    __shared__ __align__(16) int8_t xt[4][66][256];   // 67,584 B
    __shared__ float bsh[256];

    int bx = blockIdx.x;               // 0..895
    int n  = bx / 28;
    int hb = bx - n * 28;
    int h  = hb * 2;                   // output rows h, h+1
    int tid = threadIdx.x, lane = tid & 63, wv = tid >> 6;

    if (tid < 256) bsh[tid] = bias[tid];

    // expand packed sign bits -> i8 (+1/-1); borders & cols>=58 -> 0
    const uint32_t* xpb = xp + (size_t)n * PIMG;
    for (int e = tid; e < 4 * 66 * 64; e += 512) {   // 33 iters exactly
        int pr  = e / (66 * 64);
        int rem = e - pr * (66 * 64);
        int col = rem >> 6;
        int d   = rem & 63;            // output dword = 4 ci
        int prg = h + pr;              // padded global row
        bool val = (prg >= 1) & (prg <= 56) & (col >= 1) & (col <= 56);
        uint32_t wvv = 0;
        if (val) wvv = xpb[(size_t)prg * PROW + col * 8 + (d >> 3)];
        uint32_t nib = (wvv >> ((d & 7) * 4)) & 0xFu;
        uint32_t sp  = (nib * 0x00204081u) & 0x01010101u;   // bit k -> byte k
        uint32_t o   = val ? __builtin_amdgcn_perm(0u, 0x000001FFu, sp) : 0u;
        uint32_t ba  = (uint32_t)((((pr * 66 + col) << 8) | (d << 2))
                                  ^ ((col & 15) << 4));
        *(uint32_t*)((char*)&xt[0][0][0] + ba) = o;
    }
    __syncthreads();

    i32x16 acc0 = {0}, acc1 = {0}, acc2 = {0}, acc3 = {0};

    int l31  = lane & 31;
    int hi16 = (lane >> 5) << 4;
    const int8_t* wql = wq + ((size_t)(wv * 32 + l31)) * 32 + hi16;
    const char* xtb = (const char*)&xt[0][0][0];

    for (int dw = 0; dw < 3; ++dw) {
        int c0 = l31 + dw;             // col of this lane's pixel (colblk 0)
        int sw = (c0 & 15) << 4;       // (c0+32)&15 identical -> shared swizzle
        const char* xc = xtb + (c0 << 8);
        const int8_t* wa0 = wql + (size_t)(dw * 8) * 8192;   // dh=0 tap base
        #pragma unroll
        for (int c8 = 0; c8 < 8; ++c8) {
            int sx = ((c8 << 5) + hi16) ^ sw;
            // 8 B fragments: rows 0..3 x colblocks {0,+32}
            i32x4 b00 = *(const i32x4*)(xc + ((0 * 66     ) << 8) + sx);
            i32x4 b01 = *(const i32x4*)(xc + ((0 * 66 + 32) << 8) + sx);
            i32x4 b10 = *(const i32x4*)(xc + ((1 * 66     ) << 8) + sx);
            i32x4 b11 = *(const i32x4*)(xc + ((1 * 66 + 32) << 8) + sx);
            i32x4 b20 = *(const i32x4*)(xc + ((2 * 66     ) << 8) + sx);
            i32x4 b21 = *(const i32x4*)(xc + ((2 * 66 + 32) << 8) + sx);
            i32x4 b30 = *(const i32x4*)(xc + ((3 * 66     ) << 8) + sx);
            i32x4 b31 = *(const i32x4*)(xc + ((3 * 66 + 32) << 8) + sx);
            // 3 A fragments: dh = 0,1,2 (t = dh*3+dw), stride 3*8*8192
            const int8_t* wa = wa0 + (size_t)c8 * 8192;
            i32x4 a0v = *(const i32x4*)(wa);
            i32x4 a1v = *(const i32x4*)(wa + 196608);
            i32x4 a2v = *(const i32x4*)(wa + 393216);
            // pair0 (row h): b[dh][*]; pair1 (row h+1): b[dh+1][*]
            acc0 = __builtin_amdgcn_mfma_i32_32x32x32_i8(a0v, b00, acc0, 0, 0, 0);
            acc1 = __builtin_amdgcn_mfma_i32_32x32x32_i8(a0v, b01, acc1, 0, 0, 0);
            acc2 = __builtin_amdgcn_mfma_i32_32x32x32_i8(a0v, b10, acc2, 0, 0, 0);
            acc3 = __builtin_amdgcn_mfma_i32_32x32x32_i8(a0v, b11, acc3, 0, 0, 0);
            acc0 = __builtin_amdgcn_mfma_i32_32x32x32_i8(a1v, b10, acc0, 0, 0, 0);
            acc1 = __builtin_amdgcn_mfma_i32_32x32x32_i8(a1v, b11, acc1, 0, 0, 0);
            acc2 = __builtin_amdgcn_mfma_i32_32x32x32_i8(a1v, b20, acc2, 0, 0, 0);
            acc3 = __builtin_amdgcn_mfma_i32_32x32x32_i8(a1v, b21, acc3, 0, 0, 0);
            acc0 = __builtin_amdgcn_mfma_i32_32x32x32_i8(a2v, b20, acc0, 0, 0, 0);
            acc1 = __builtin_amdgcn_mfma_i32_32x32x32_i8(a2v, b21, acc1, 0, 0, 0);
            acc2 = __builtin_amdgcn_mfma_i32_32x32x32_i8(a2v, b30, acc2, 0, 0, 0);
            acc3 = __builtin_amdgcn_mfma_i32_32x32x32_i8(a2v, b31, acc3, 0, 0, 0);
        }
    }

    // epilogue: C col = pixel (lane&31), row = (r&3)+8*(r>>2)+4*(lane>>5)
    #define EPI(ACC, PT) { \
        int pix = ((PT) & 1) * 32 + l31; \
        if (pix < WW) { \
            int hg = h + ((PT) >> 1); \
            float* op = out + (size_t)n * COUT * HW + (size_t)hg * WW + pix; \
            _Pragma("unroll") \
            for (int r = 0; r < 16; ++r) { \
                int row = (r & 3) + 8 * (r >> 2) + ((lane >> 5) << 2); \
                int co  = (wv << 5) + row; \
                op[(size_t)co * HW] = (float)ACC[r] + bsh[co]; \
            } \
        } }
    EPI(acc0, 0) EPI(acc1, 1) EPI(acc2, 2) EPI(acc3, 3)
    #undef EPI
}

extern "C" void kernel_launch(void* const* d_in, const int* in_sizes, int n_in,
                              void* d_out, int out_size, void* d_ws, size_t ws_size,
                              hipStream_t stream) {
    const float* x = (const float*)d_in[0];
    const float* w = (const float*)d_in[1];
    const float* b = (const float*)d_in[2];
    float* out = (float*)d_out;

    uint32_t* xp = (uint32_t*)d_ws;
    int8_t*   wq = (int8_t*)((char*)d_ws + XP_BYTES);

    pack_x_kernel<<<NPIX / 64, 256, 0, stream>>>(x, xp);
    pack_w2_kernel<<<COUT, 256, 0, stream>>>(w, wq);

    bconv_kernel<<<NBATCH * (HH / 2), 512, 0, stream>>>(xp, wq, b, out);
}

// Round 10
// 97.170 us; speedup vs baseline: 1.8959x; 1.0875x over previous
//
#include <hip/hip_runtime.h>
#include <stdint.h>

// BConv2d via MFMA i8 implicit GEMM.
// out = conv2d(sign(x), sign(w), pad=1) + b ; N=32, Cin=256, H=W=56, Cout=256, K=3.
//
// sign as i8 {+1,-1}, zero padding as i8 0 (exact, no border correction).
// conv = 9 tap-shifted GEMMs, K=256, i32 acc via v_mfma_i32_32x32x32_i8.
// C/D layout: col=lane&31, row=(reg&3)+8*(reg>>2)+4*(lane>>5) (verified R8/R9).
//
// R9 lesson: with launch_bounds(512,4) the unified VGPR budget is 128; 4
// accumulators = 64 AGPR left only 64 arch VGPRs -> compiler had no room to
// hoist loads across k-groups -> L2/LDS latency fully exposed (MfmaUtil 27%
// == the MFMA pipe floor share; dur unchanged when conflicts went 8M->0).
// R10: two sequential colblk passes, 2 accs each (32 AGPR) -> ~25-50 regs of
// scheduler slack inside the fully-unrolled c8 window. B-frags b1,b2 shared
// by the two row-accs: 4 ds_read + 3 A-loads + 6 MFMA per (dw,c8).

#define NBATCH 32
#define CIN    256
#define COUT   256
#define HH     56
#define WW     56
#define HW     (HH*WW)          // 3136
#define NPIX   (NBATCH*HW)      // 100352

#define PW    58                // padded bit-image width/height
#define PROW  (PW*8)            // 464 words per padded row
#define PIMG  (PW*PW*8)         // 26912 words per padded image

#define XP_BYTES  ((size_t)NBATCH * PIMG * 4)  // 3,444,736 (16-aligned)
#define WQ_BYTES  ((size_t)9 * 8 * 256 * 32)   // 589,824

typedef int i32x4  __attribute__((ext_vector_type(4)));
typedef int i32x16 __attribute__((ext_vector_type(16)));

// ---- pack x bits: wave handles 64 channels (2 words) for 64 pixels
__global__ __launch_bounds__(256) void pack_x_kernel(
    const float* __restrict__ x, uint32_t* __restrict__ xp)
{
    int lane = threadIdx.x & 63;
    int wv   = threadIdx.x >> 6;               // 0..3 -> channel group
    int pix  = blockIdx.x * 64 + lane;         // 1568 blocks * 64 == NPIX
    int n  = pix / HW;
    int hw = pix - n * HW;
    int h  = hw / WW;
    int w_ = hw - h * WW;
    const float* xb = x + ((size_t)n * CIN + (size_t)wv * 64) * HW + hw;

    uint32_t w0 = 0, w1 = 0;
    #pragma unroll
    for (int j = 0; j < 32; ++j) {
        w0 |= (xb[(size_t)j * HW]        >= 0.0f ? 1u : 0u) << j;
        w1 |= (xb[(size_t)(j + 32) * HW] >= 0.0f ? 1u : 0u) << j;
    }
    uint32_t* dst = xp + (size_t)n * PIMG + (size_t)(h + 1) * PROW
                       + (size_t)(w_ + 1) * 8 + wv * 2;
    *(uint2*)dst = make_uint2(w0, w1);
}

// ---- pack w -> i8 {+1,-1}, layout wq[t][c8][co][slot], slot = ci&31
__global__ __launch_bounds__(256) void pack_w2_kernel(
    const float* __restrict__ w, int8_t* __restrict__ wq)
{
    int co = blockIdx.x, ci = threadIdx.x;
    const float* wb = w + ((size_t)co * CIN + ci) * 9;
    int c8 = ci >> 5, s = ci & 31;
    #pragma unroll
    for (int t = 0; t < 9; ++t) {
        wq[((size_t)(t * 8 + c8) * 256 + co) * 32 + s] =
            (wb[t] >= 0.0f) ? (int8_t)1 : (int8_t)-1;
    }
}

// ---- conv
__global__ __launch_bounds__(512, 4) void bconv_kernel(
    const uint32_t* __restrict__ xp, const int8_t* __restrict__ wq,
    const float* __restrict__ bias, float* __restrict__ out)
{
    __shared__ __align__(16) int8_t xt[4][66][256];   // 67,584 B
    __shared__ float bsh[256];

    int bx = blockIdx.x;               // 0..895
    int n  = bx / 28;
    int hb = bx - n * 28;
    int h  = hb * 2;                   // output rows h, h+1
    int tid = threadIdx.x, lane = tid & 63, wv = tid >> 6;

    if (tid < 256) bsh[tid] = bias[tid];

    // expand packed sign bits -> i8 (+1/-1); borders & cols>=58 -> 0
    const uint32_t* xpb = xp + (size_t)n * PIMG;
    for (int e = tid; e < 4 * 66 * 64; e += 512) {   // 33 iters exactly
        int pr  = e / (66 * 64);
        int rem = e - pr * (66 * 64);
        int col = rem >> 6;
        int d   = rem & 63;            // output dword = 4 ci
        int prg = h + pr;              // padded global row
        bool val = (prg >= 1) & (prg <= 56) & (col >= 1) & (col <= 56);
        uint32_t wvv = 0;
        if (val) wvv = xpb[(size_t)prg * PROW + col * 8 + (d >> 3)];
        uint32_t nib = (wvv >> ((d & 7) * 4)) & 0xFu;
        uint32_t sp  = (nib * 0x00204081u) & 0x01010101u;   // bit k -> byte k
        uint32_t o   = val ? __builtin_amdgcn_perm(0u, 0x000001FFu, sp) : 0u;
        uint32_t ba  = (uint32_t)((((pr * 66 + col) << 8) | (d << 2))
                                  ^ ((col & 15) << 4));
        *(uint32_t*)((char*)&xt[0][0][0] + ba) = o;
    }
    __syncthreads();

    int l31  = lane & 31;
    int hi16 = (lane >> 5) << 4;
    const int8_t* wql = wq + ((size_t)(wv * 32 + l31)) * 32 + hi16;
    const char* xtb = (const char*)&xt[0][0][0];

    for (int cb = 0; cb < 2; ++cb) {
        i32x16 accA = {0}, accB = {0};     // output rows h, h+1

        for (int dw = 0; dw < 3; ++dw) {
            int col = l31 + cb * 32 + dw;  // this lane's xt column
            int sw  = (col & 15) << 4;
            const char* xc = xtb + (col << 8);
            const int8_t* wa0 = wql + (size_t)(dw * 8) * 8192;  // dh=0 tap
            #pragma unroll
            for (int c8 = 0; c8 < 8; ++c8) {
                int sx = ((c8 << 5) + hi16) ^ sw;
                i32x4 b0 = *(const i32x4*)(xc + ((0 * 66) << 8) + sx);
                i32x4 b1 = *(const i32x4*)(xc + ((1 * 66) << 8) + sx);
                i32x4 b2 = *(const i32x4*)(xc + ((2 * 66) << 8) + sx);
                i32x4 b3 = *(const i32x4*)(xc + ((3 * 66) << 8) + sx);
                const int8_t* wa = wa0 + (size_t)c8 * 8192;
                i32x4 a0v = *(const i32x4*)(wa);
                i32x4 a1v = *(const i32x4*)(wa + 196608);
                i32x4 a2v = *(const i32x4*)(wa + 393216);
                accA = __builtin_amdgcn_mfma_i32_32x32x32_i8(a0v, b0, accA, 0, 0, 0);
                accB = __builtin_amdgcn_mfma_i32_32x32x32_i8(a0v, b1, accB, 0, 0, 0);
                accA = __builtin_amdgcn_mfma_i32_32x32x32_i8(a1v, b1, accA, 0, 0, 0);
                accB = __builtin_amdgcn_mfma_i32_32x32x32_i8(a1v, b2, accB, 0, 0, 0);
                accA = __builtin_amdgcn_mfma_i32_32x32x32_i8(a2v, b2, accA, 0, 0, 0);
                accB = __builtin_amdgcn_mfma_i32_32x32x32_i8(a2v, b3, accB, 0, 0, 0);
            }
        }

        // epilogue: C col=pixel(lane&31 within colblk), row=(r&3)+8*(r>>2)+4*(lane>>5)
        int pix = cb * 32 + l31;
        if (pix < WW) {
            float* op = out + (size_t)n * COUT * HW + (size_t)h * WW + pix;
            #pragma unroll
            for (int r = 0; r < 16; ++r) {
                int row = (r & 3) + 8 * (r >> 2) + ((lane >> 5) << 2);
                int co  = (wv << 5) + row;
                float bb = bsh[co];
                op[(size_t)co * HW]      = (float)accA[r] + bb;
                op[(size_t)co * HW + WW] = (float)accB[r] + bb;
            }
        }
    }
}

extern "C" void kernel_launch(void* const* d_in, const int* in_sizes, int n_in,
                              void* d_out, int out_size, void* d_ws, size_t ws_size,
                              hipStream_t stream) {
    const float* x = (const float*)d_in[0];
    const float* w = (const float*)d_in[1];
    const float* b = (const float*)d_in[2];
    float* out = (float*)d_out;

    uint32_t* xp = (uint32_t*)d_ws;
    int8_t*   wq = (int8_t*)((char*)d_ws + XP_BYTES);

    pack_x_kernel<<<NPIX / 64, 256, 0, stream>>>(x, xp);
    pack_w2_kernel<<<COUT, 256, 0, stream>>>(w, wq);

    bconv_kernel<<<NBATCH * (HH / 2), 512, 0, stream>>>(xp, wq, b, out);
}